// Round 3
// baseline (474.100 us; speedup 1.0000x reference)
//
#include <hip/hip_runtime.h>
#include <math.h>

#define EPSF 1e-12f

// N=64, C=512, P=1600, K=64
// Fused kernel: per block = (one n, one 320-p group), 5 chunks of 64 p.
// Per chunk: stage x fp32->bf16 to LDS [c][p] (stride 72, dbuf) ->
// GEMM1 (logits, ss fused into A-frag reads) -> softmax -> a' to LDS ->
// GEMM2 accumulate D[64k][512c] in registers. Epilogue: atomicAdd to out.
// ws: Wb bf16 @0 (65,536) | asum f32 @65,536 | rn2 @81,920 | gn @98,304

typedef short bf16x8 __attribute__((ext_vector_type(8)));
typedef float f32x4  __attribute__((ext_vector_type(4)));

__device__ __forceinline__ ushort f2b(float x) {
    unsigned u = __float_as_uint(x);
    return (ushort)((u + 0x7fffu + ((u >> 16) & 1u)) >> 16);
}
__device__ __forceinline__ float b2f(ushort h) {
    return __uint_as_float(((unsigned)h) << 16);
}

// ------------------------------------------------- K0: Wb[k][c] = bf16(W)
__global__ __launch_bounds__(256) void k0_wb(const float* __restrict__ W,
                                             ushort* __restrict__ Wb) {
    int i = blockIdx.x * 256 + threadIdx.x;
    if (i < 64 * 512) Wb[i] = f2b(W[i]);
}

// ------------------------------------------------- fused mega-kernel
#define XSTR 72   // LDS p-stride (elems): 144 B, 16-B aligned, bank-friendly

__global__ __launch_bounds__(256, 1) void k_fused(const float* __restrict__ x,
                                                  const ushort* __restrict__ Wb,
                                                  float* __restrict__ out,
                                                  float* __restrict__ asum) {
    const int n  = blockIdx.y;
    const int p0 = blockIdx.x * 320;
    const int tid = threadIdx.x;
    const int wv = tid >> 6, lane = tid & 63;
    const int q = lane >> 4, l15 = lane & 15;

    __shared__ ushort xs[2][512 * XSTR] __attribute__((aligned(16)));  // 2x73,728 B
    __shared__ ushort as_[64 * XSTR]    __attribute__((aligned(16)));  // 9,216 B

    // staging role: thread covers row c = it*64 + (tid>>2), p-span (tid&3)*16..+16
    const int srow = tid >> 2;
    const int spo  = (tid & 3) * 16;
    const float* xg = x + ((size_t)(n * 512 + srow) * 1600) + p0 + spo;

    f32x4 acc2[32] = {};       // GEMM2 accumulator: wave wv -> k-tile wv, all 512 c
    float asum_acc[4] = {0.f, 0.f, 0.f, 0.f};

    // ---- prologue: stage chunk 0 into xs[0]
    {
        float4 fr[8][4];
        #pragma unroll
        for (int it = 0; it < 8; it++)
            #pragma unroll
            for (int u = 0; u < 4; u++)
                fr[it][u] = *(const float4*)(xg + (size_t)it * 64 * 1600 + u * 4);
        #pragma unroll
        for (int it = 0; it < 8; it++) {
            ushort h[16] __attribute__((aligned(16)));
            #pragma unroll
            for (int u = 0; u < 4; u++) {
                h[u * 4 + 0] = f2b(fr[it][u].x);
                h[u * 4 + 1] = f2b(fr[it][u].y);
                h[u * 4 + 2] = f2b(fr[it][u].z);
                h[u * 4 + 3] = f2b(fr[it][u].w);
            }
            ushort* d = &xs[0][(it * 64 + srow) * XSTR + spo];
            ((uint4*)d)[0] = ((const uint4*)h)[0];
            ((uint4*)d)[1] = ((const uint4*)h)[1];
        }
    }
    __syncthreads();

    for (int ch = 0; ch < 5; ch++) {
        const int cur = ch & 1, nxt = cur ^ 1;

        // ---- 1. prefetch chunk ch+1 (loads in flight through GEMM1/GEMM2)
        float4 fr[8][4];
        if (ch < 4) {
            #pragma unroll
            for (int it = 0; it < 8; it++)
                #pragma unroll
                for (int u = 0; u < 4; u++)
                    fr[it][u] = *(const float4*)(xg + (size_t)it * 64 * 1600 + (ch + 1) * 64 + u * 4);
        }

        // ---- 2. GEMM1: D[16p][64k] per wave (p rows = wv*16 + l15), K = 512 c
        const ushort* xcur = xs[cur];
        const int pl = wv * 16 + l15;   // chunk-local p row (A-frag row)
        f32x4 acc1[4] = {};
        float ssp = 0.f;
        for (int kc = 0; kc < 16; kc++) {
            bf16x8 af;
            #pragma unroll
            for (int j = 0; j < 8; j++) {
                ushort h = xcur[(kc * 32 + q * 8 + j) * XSTR + pl];
                af[j] = (short)h;
                float f = b2f(h);
                ssp = fmaf(f, f, ssp);   // lane's quarter of sum_c x^2 for row pl
            }
            #pragma unroll
            for (int nt = 0; nt < 4; nt++) {
                bf16x8 bw = *(const bf16x8*)(Wb + (nt * 16 + l15) * 512 + kc * 32 + q * 8);
                acc1[nt] = __builtin_amdgcn_mfma_f32_16x16x32_bf16(af, bw, acc1[nt], 0, 0, 0);
            }
        }
        // complete ss across the 4 q-lanes sharing row pl
        ssp += __shfl_xor(ssp, 16, 64);
        ssp += __shfl_xor(ssp, 32, 64);
        float rn_l = 1.f / fmaxf(sqrtf(ssp), EPSF);   // rn for p-row l15
        float rnv[4];
        #pragma unroll
        for (int r = 0; r < 4; r++) rnv[r] = __shfl(rn_l, q * 4 + r, 64);  // rn for D-row q*4+r

        // softmax over k (64 = 4 nt in-lane x 16 l15 cross-lane)  [R1-verified]
        float v[4][4];
        float mx[4] = {-3.4e38f, -3.4e38f, -3.4e38f, -3.4e38f};
        #pragma unroll
        for (int nt = 0; nt < 4; nt++)
            #pragma unroll
            for (int r = 0; r < 4; r++) {
                v[nt][r] = acc1[nt][r] * rnv[r];
                mx[r] = fmaxf(mx[r], v[nt][r]);
            }
        #pragma unroll
        for (int s = 1; s <= 8; s <<= 1)
            #pragma unroll
            for (int r = 0; r < 4; r++) mx[r] = fmaxf(mx[r], __shfl_xor(mx[r], s, 64));
        float sm[4] = {0.f, 0.f, 0.f, 0.f};
        #pragma unroll
        for (int nt = 0; nt < 4; nt++)
            #pragma unroll
            for (int r = 0; r < 4; r++) { v[nt][r] = __expf(v[nt][r] - mx[r]); sm[r] += v[nt][r]; }
        #pragma unroll
        for (int s = 1; s <= 8; s <<= 1)
            #pragma unroll
            for (int r = 0; r < 4; r++) sm[r] += __shfl_xor(sm[r], s, 64);
        float inv[4];
        #pragma unroll
        for (int r = 0; r < 4; r++) inv[r] = 1.f / sm[r];
        #pragma unroll
        for (int nt = 0; nt < 4; nt++)
            #pragma unroll
            for (int r = 0; r < 4; r++) v[nt][r] *= inv[r];

        // asum partials (sum over this wave's 16 p rows), accumulate across chunks
        #pragma unroll
        for (int nt = 0; nt < 4; nt++) {
            float t = v[nt][0] + v[nt][1] + v[nt][2] + v[nt][3];
            t += __shfl_xor(t, 16, 64);
            t += __shfl_xor(t, 32, 64);
            asum_acc[nt] += t;
        }

        // a' = a*rn -> bf16 -> as_[k][p_local]
        #pragma unroll
        for (int nt = 0; nt < 4; nt++)
            #pragma unroll
            for (int r = 0; r < 4; r++)
                as_[(nt * 16 + l15) * XSTR + wv * 16 + q * 4 + r] = f2b(v[nt][r] * rnv[r]);

        __syncthreads();   // a' visible to all waves; GEMM1 reads of xs[cur] done

        // ---- 3. GEMM2: acc2 += a'[k-tile wv][p] * x[c][p], K = 64 p (2 kc steps)
        #pragma unroll
        for (int kc = 0; kc < 2; kc++) {
            bf16x8 afr = *(const bf16x8*)(as_ + (wv * 16 + l15) * XSTR + kc * 32 + q * 8);
            #pragma unroll
            for (int nt = 0; nt < 32; nt++) {
                bf16x8 b = *(const bf16x8*)(xcur + (nt * 16 + l15) * XSTR + kc * 32 + q * 8);
                acc2[nt] = __builtin_amdgcn_mfma_f32_16x16x32_bf16(afr, b, acc2[nt], 0, 0, 0);
            }
        }

        // ---- 4. convert prefetched chunk into xs[nxt] (no conflict with cur/as_)
        if (ch < 4) {
            #pragma unroll
            for (int it = 0; it < 8; it++) {
                ushort h[16] __attribute__((aligned(16)));
                #pragma unroll
                for (int u = 0; u < 4; u++) {
                    h[u * 4 + 0] = f2b(fr[it][u].x);
                    h[u * 4 + 1] = f2b(fr[it][u].y);
                    h[u * 4 + 2] = f2b(fr[it][u].z);
                    h[u * 4 + 3] = f2b(fr[it][u].w);
                }
                ushort* d = &xs[nxt][(it * 64 + srow) * XSTR + spo];
                ((uint4*)d)[0] = ((const uint4*)h)[0];
                ((uint4*)d)[1] = ((const uint4*)h)[1];
            }
        }
        __syncthreads();   // xs[nxt] ready; as_/xs[cur] fully consumed
    }

    // ---- epilogue: asum + out atomics
    if (lane < 16) {
        #pragma unroll
        for (int nt = 0; nt < 4; nt++)
            atomicAdd(&asum[n * 64 + nt * 16 + l15], asum_acc[nt]);
    }
    float* ob = out + (size_t)n * 32768 + l15;
    #pragma unroll
    for (int nt = 0; nt < 32; nt++)
        #pragma unroll
        for (int r = 0; r < 4; r++)
            atomicAdd(ob + (wv * 16 + q * 4 + r) * 512 + nt * 16, acc2[nt][r]);
}

// ------------------------------------------------- K4a: rownorm2[n,k] = sum_c (raw - asum*cent)^2
__global__ __launch_bounds__(256) void k4a_rownorm(const float* __restrict__ vraw,
                                                   const float* __restrict__ asum,
                                                   const float* __restrict__ cent,
                                                   float* __restrict__ rn2) {
    int row  = blockIdx.x * 4 + (threadIdx.x >> 6);
    int lane = threadIdx.x & 63;
    int k = row & 63;
    const float4* vp = (const float4*)(vraw + (size_t)row * 512 + lane * 8);
    const float4* cp = (const float4*)(cent + k * 512 + lane * 8);
    float as = asum[row];
    float4 v0 = vp[0], v1 = vp[1], c0 = cp[0], c1 = cp[1];
    float s = 0.f, t;
    t = v0.x - as * c0.x; s = fmaf(t, t, s);
    t = v0.y - as * c0.y; s = fmaf(t, t, s);
    t = v0.z - as * c0.z; s = fmaf(t, t, s);
    t = v0.w - as * c0.w; s = fmaf(t, t, s);
    t = v1.x - as * c1.x; s = fmaf(t, t, s);
    t = v1.y - as * c1.y; s = fmaf(t, t, s);
    t = v1.z - as * c1.z; s = fmaf(t, t, s);
    t = v1.w - as * c1.w; s = fmaf(t, t, s);
    #pragma unroll
    for (int off = 32; off > 0; off >>= 1) s += __shfl_down(s, off, 64);
    if (lane == 0) rn2[row] = s;
}

// ------------------------------------------------- K4b: gn[n]
__global__ __launch_bounds__(64) void k4b_gn(const float* __restrict__ rn2,
                                             float* __restrict__ gn) {
    int n = blockIdx.x, k = threadIdx.x;
    float t = rn2[n * 64 + k];
    float d = fmaxf(sqrtf(t), EPSF);
    float r = t / (d * d);
    #pragma unroll
    for (int off = 32; off > 0; off >>= 1) r += __shfl_down(r, off, 64);
    if (k == 0) gn[n] = fmaxf(sqrtf(r), EPSF);
}

// ------------------------------------------------- K4c: final normalize
__global__ __launch_bounds__(256) void k4c_final(float* __restrict__ vout,
                                                 const float* __restrict__ asum,
                                                 const float* __restrict__ cent,
                                                 const float* __restrict__ rn2,
                                                 const float* __restrict__ gn) {
    int gid = blockIdx.x * 256 + threadIdx.x;
    int idx4 = gid * 4;
    int row = idx4 >> 9;
    int n = row >> 6, k = row & 63, c = idx4 & 511;
    float4 v  = *(const float4*)(vout + idx4);
    float4 cv = *(const float4*)(cent + k * 512 + c);
    float as = asum[row];
    float inv = 1.f / (fmaxf(sqrtf(rn2[row]), EPSF) * gn[n]);
    v.x = (v.x - as * cv.x) * inv;
    v.y = (v.y - as * cv.y) * inv;
    v.z = (v.z - as * cv.z) * inv;
    v.w = (v.w - as * cv.w) * inv;
    *(float4*)(vout + idx4) = v;
}

// -------------------------------------------------
extern "C" void kernel_launch(void* const* d_in, const int* in_sizes, int n_in,
                              void* d_out, int out_size, void* d_ws, size_t ws_size,
                              hipStream_t stream) {
    const float* x    = (const float*)d_in[0];
    const float* W    = (const float*)d_in[1];
    const float* cent = (const float*)d_in[2];
    float* out = (float*)d_out;
    char* ws = (char*)d_ws;

    ushort* Wb   = (ushort*)(ws + 0);
    float*  asum = (float*)(ws + 65536);
    float*  rn2  = (float*)(ws + 81920);
    float*  gn   = (float*)(ws + 98304);

    hipMemsetAsync(asum, 0, 64 * 64 * sizeof(float), stream);
    hipMemsetAsync(d_out, 0, (size_t)out_size * sizeof(float), stream);

    hipLaunchKernelGGL(k0_wb,       dim3(128),     dim3(256), 0, stream, W, Wb);
    hipLaunchKernelGGL(k_fused,     dim3(5, 64),   dim3(256), 0, stream, x, Wb, out, asum);
    hipLaunchKernelGGL(k4a_rownorm, dim3(1024),    dim3(256), 0, stream, out, asum, cent, rn2);
    hipLaunchKernelGGL(k4b_gn,      dim3(64),      dim3(64),  0, stream, rn2, gn);
    hipLaunchKernelGGL(k4c_final,   dim3(2048),    dim3(256), 0, stream, out, asum, cent, rn2, gn);
}

// Round 4
// 401.152 us; speedup vs baseline: 1.1818x; 1.1818x over previous
//
#include <hip/hip_runtime.h>
#include <math.h>

#define EPSF 1e-12f

// N=64, C=512, P=1600, K=64
// Pipeline (all high-occupancy, no transpose anywhere):
//   k0 : Wb[k][c] = bf16(W)
//   k2g: GEMM1 logits = x^T W^T, A-frags read DIRECTLY from global x [c][p]
//        (lane l15 = consecutive p -> coalesced), ss/rn fused, softmax in-reg,
//        a' = a*rn -> bf16 a_t[n][k][p]; asum atomics.
//   k3g: GEMM2 vlad_raw[k][c] += a'[k][p] x[c][p] (bf16 MFMA, x converted on the fly),
//        5 p-chunks, atomicAdd into zeroed d_out.
//   k4a/b/c: intra-norm + global norm epilogue (R2-verified).
// ws: a_t bf16 @0 (13,107,200) | Wb @13,107,200 | asum @13,172,736
//     | rn2 @13,189,120 | gn @13,205,504

typedef short bf16x8 __attribute__((ext_vector_type(8)));
typedef float f32x4  __attribute__((ext_vector_type(4)));

__device__ __forceinline__ ushort f2b(float x) {
    unsigned u = __float_as_uint(x);
    return (ushort)((u + 0x7fffu + ((u >> 16) & 1u)) >> 16);
}

// ------------------------------------------------- K0: Wb[k][c] = bf16(W)
__global__ __launch_bounds__(256) void k0_wb(const float* __restrict__ W,
                                             ushort* __restrict__ Wb) {
    int i = blockIdx.x * 256 + threadIdx.x;
    if (i < 64 * 512) Wb[i] = f2b(W[i]);
}

// ------------------------------------------------- K2g: GEMM1 + softmax + a_t
// grid (25 ptiles of 64, 64 n), 256 thr. Wave: D[16p][64k], K=512 c.
__global__ __launch_bounds__(256) void k2g_gemm1(const float* __restrict__ x,
                                                 const ushort* __restrict__ Wb,
                                                 ushort* __restrict__ a_t,
                                                 float* __restrict__ asum) {
    const int n = blockIdx.y;
    const int p0 = blockIdx.x * 64;
    const int wv = threadIdx.x >> 6, lane = threadIdx.x & 63;
    const int q = lane >> 4, l15 = lane & 15;
    const int pw = p0 + wv * 16;

    // A-frag source: x[n][c = kc*32 + q*8 + j][pw + l15]  (lanes coalesced in p)
    const float* xq = x + (size_t)n * 512 * 1600 + (size_t)q * 8 * 1600 + pw + l15;
    const ushort* brow = Wb + l15 * 512 + q * 8;

    f32x4 acc[4] = {};
    float ssp = 0.f;
    for (int kc = 0; kc < 16; kc++) {
        float fv[8];
        #pragma unroll
        for (int j = 0; j < 8; j++) fv[j] = xq[(size_t)(kc * 32 + j) * 1600];
        bf16x8 af;
        #pragma unroll
        for (int j = 0; j < 8; j++) {
            ssp = fmaf(fv[j], fv[j], ssp);     // fp32-accurate sum of squares
            af[j] = (short)f2b(fv[j]);
        }
        #pragma unroll
        for (int nt = 0; nt < 4; nt++) {
            bf16x8 bw = *(const bf16x8*)(brow + nt * 16 * 512 + kc * 32);
            acc[nt] = __builtin_amdgcn_mfma_f32_16x16x32_bf16(af, bw, acc[nt], 0, 0, 0);
        }
    }
    // complete ss across the 4 q-lanes sharing p-row l15
    ssp += __shfl_xor(ssp, 16, 64);
    ssp += __shfl_xor(ssp, 32, 64);
    float rn_l = 1.f / fmaxf(sqrtf(ssp), EPSF);
    float rnv[4];
    #pragma unroll
    for (int r = 0; r < 4; r++) rnv[r] = __shfl(rn_l, q * 4 + r, 64);  // rn for D-row q*4+r

    // softmax over k (4 nt in-lane x 16 l15 cross-lane)  [R1/R3-verified]
    float v[4][4];
    float mx[4] = {-3.4e38f, -3.4e38f, -3.4e38f, -3.4e38f};
    #pragma unroll
    for (int nt = 0; nt < 4; nt++)
        #pragma unroll
        for (int r = 0; r < 4; r++) {
            v[nt][r] = acc[nt][r] * rnv[r];
            mx[r] = fmaxf(mx[r], v[nt][r]);
        }
    #pragma unroll
    for (int s = 1; s <= 8; s <<= 1)
        #pragma unroll
        for (int r = 0; r < 4; r++) mx[r] = fmaxf(mx[r], __shfl_xor(mx[r], s, 64));
    float sm[4] = {0.f, 0.f, 0.f, 0.f};
    #pragma unroll
    for (int nt = 0; nt < 4; nt++)
        #pragma unroll
        for (int r = 0; r < 4; r++) { v[nt][r] = __expf(v[nt][r] - mx[r]); sm[r] += v[nt][r]; }
    #pragma unroll
    for (int s = 1; s <= 8; s <<= 1)
        #pragma unroll
        for (int r = 0; r < 4; r++) sm[r] += __shfl_xor(sm[r], s, 64);
    float inv[4];
    #pragma unroll
    for (int r = 0; r < 4; r++) inv[r] = 1.f / sm[r];
    #pragma unroll
    for (int nt = 0; nt < 4; nt++)
        #pragma unroll
        for (int r = 0; r < 4; r++) v[nt][r] *= inv[r];

    // asum partials: column k = nt*16 + l15, sum over this wave's 16 p-rows
    #pragma unroll
    for (int nt = 0; nt < 4; nt++) {
        float t = v[nt][0] + v[nt][1] + v[nt][2] + v[nt][3];
        t += __shfl_xor(t, 16, 64);
        t += __shfl_xor(t, 32, 64);
        if (lane < 16) atomicAdd(&asum[n * 64 + nt * 16 + lane], t);
    }

    // a' = a*rn -> bf16, LDS bounce [k][p_local], then b128 global write  [R2-verified]
    __shared__ ushort abuf[4][64 * 24];
    #pragma unroll
    for (int nt = 0; nt < 4; nt++)
        #pragma unroll
        for (int r = 0; r < 4; r++)
            abuf[wv][(nt * 16 + l15) * 24 + q * 4 + r] = f2b(v[nt][r] * rnv[r]);
    __syncthreads();
    ushort* dst = a_t + ((size_t)n * 64 + lane) * 1600 + pw;
    const ushort* srcl = &abuf[wv][lane * 24];
    *(uint4*)(dst)     = *(const uint4*)(srcl);
    *(uint4*)(dst + 8) = *(const uint4*)(srcl + 8);
}

// ------------------------------------------------- K3g: GEMM2  [R2-verified]
// D[k][c]: block 64k x 256c, K=320 p per chunk. grid (2 ctiles, 64 n, 5 pchunks).
__global__ __launch_bounds__(256) void k3_gemm2(const ushort* __restrict__ a_t,
                                                const float* __restrict__ x,
                                                float* __restrict__ out) {
    const int n = blockIdx.y;
    const int c0 = blockIdx.x * 256;
    const int p0 = blockIdx.z * 320;
    const int wv = threadIdx.x >> 6, lane = threadIdx.x & 63;
    const int q = lane >> 4, l15 = lane & 15;
    const int cw = c0 + wv * 64;

    const ushort* abase = a_t + ((size_t)n * 64 + l15) * 1600 + p0 + q * 8;
    const float*  xbase = x + ((size_t)n * 512 + cw + l15) * 1600 + p0 + q * 8;

    f32x4 acc[4][4] = {};
    for (int pc = 0; pc < 320; pc += 32) {
        bf16x8 af[4];
        #pragma unroll
        for (int mt = 0; mt < 4; mt++)
            af[mt] = *(const bf16x8*)(abase + (size_t)mt * 16 * 1600 + pc);
        bf16x8 bf[4];
        #pragma unroll
        for (int nt = 0; nt < 4; nt++) {
            const float* xr = xbase + (size_t)nt * 16 * 1600 + pc;
            float4 f0 = *(const float4*)(xr);
            float4 f1 = *(const float4*)(xr + 4);
            bf16x8 b;
            b[0] = (short)f2b(f0.x); b[1] = (short)f2b(f0.y);
            b[2] = (short)f2b(f0.z); b[3] = (short)f2b(f0.w);
            b[4] = (short)f2b(f1.x); b[5] = (short)f2b(f1.y);
            b[6] = (short)f2b(f1.z); b[7] = (short)f2b(f1.w);
            bf[nt] = b;
        }
        #pragma unroll
        for (int mt = 0; mt < 4; mt++)
            #pragma unroll
            for (int nt = 0; nt < 4; nt++)
                acc[mt][nt] = __builtin_amdgcn_mfma_f32_16x16x32_bf16(af[mt], bf[nt], acc[mt][nt], 0, 0, 0);
    }
    float* ob = out + (size_t)n * 32768 + cw + l15;
    #pragma unroll
    for (int mt = 0; mt < 4; mt++)
        #pragma unroll
        for (int nt = 0; nt < 4; nt++)
            #pragma unroll
            for (int r = 0; r < 4; r++)
                atomicAdd(ob + (mt * 16 + q * 4 + r) * 512 + nt * 16, acc[mt][nt][r]);
}

// ------------------------------------------------- K4a: rownorm2[n,k]
__global__ __launch_bounds__(256) void k4a_rownorm(const float* __restrict__ vraw,
                                                   const float* __restrict__ asum,
                                                   const float* __restrict__ cent,
                                                   float* __restrict__ rn2) {
    int row  = blockIdx.x * 4 + (threadIdx.x >> 6);
    int lane = threadIdx.x & 63;
    int k = row & 63;
    const float4* vp = (const float4*)(vraw + (size_t)row * 512 + lane * 8);
    const float4* cp = (const float4*)(cent + k * 512 + lane * 8);
    float as = asum[row];
    float4 v0 = vp[0], v1 = vp[1], c0 = cp[0], c1 = cp[1];
    float s = 0.f, t;
    t = v0.x - as * c0.x; s = fmaf(t, t, s);
    t = v0.y - as * c0.y; s = fmaf(t, t, s);
    t = v0.z - as * c0.z; s = fmaf(t, t, s);
    t = v0.w - as * c0.w; s = fmaf(t, t, s);
    t = v1.x - as * c1.x; s = fmaf(t, t, s);
    t = v1.y - as * c1.y; s = fmaf(t, t, s);
    t = v1.z - as * c1.z; s = fmaf(t, t, s);
    t = v1.w - as * c1.w; s = fmaf(t, t, s);
    #pragma unroll
    for (int off = 32; off > 0; off >>= 1) s += __shfl_down(s, off, 64);
    if (lane == 0) rn2[row] = s;
}

// ------------------------------------------------- K4b: gn[n]
__global__ __launch_bounds__(64) void k4b_gn(const float* __restrict__ rn2,
                                             float* __restrict__ gn) {
    int n = blockIdx.x, k = threadIdx.x;
    float t = rn2[n * 64 + k];
    float d = fmaxf(sqrtf(t), EPSF);
    float r = t / (d * d);
    #pragma unroll
    for (int off = 32; off > 0; off >>= 1) r += __shfl_down(r, off, 64);
    if (k == 0) gn[n] = fmaxf(sqrtf(r), EPSF);
}

// ------------------------------------------------- K4c: final normalize
__global__ __launch_bounds__(256) void k4c_final(float* __restrict__ vout,
                                                 const float* __restrict__ asum,
                                                 const float* __restrict__ cent,
                                                 const float* __restrict__ rn2,
                                                 const float* __restrict__ gn) {
    int gid = blockIdx.x * 256 + threadIdx.x;
    int idx4 = gid * 4;
    int row = idx4 >> 9;
    int n = row >> 6, k = row & 63, c = idx4 & 511;
    float4 v  = *(const float4*)(vout + idx4);
    float4 cv = *(const float4*)(cent + k * 512 + c);
    float as = asum[row];
    float inv = 1.f / (fmaxf(sqrtf(rn2[row]), EPSF) * gn[n]);
    v.x = (v.x - as * cv.x) * inv;
    v.y = (v.y - as * cv.y) * inv;
    v.z = (v.z - as * cv.z) * inv;
    v.w = (v.w - as * cv.w) * inv;
    *(float4*)(vout + idx4) = v;
}

// -------------------------------------------------
extern "C" void kernel_launch(void* const* d_in, const int* in_sizes, int n_in,
                              void* d_out, int out_size, void* d_ws, size_t ws_size,
                              hipStream_t stream) {
    const float* x    = (const float*)d_in[0];
    const float* W    = (const float*)d_in[1];
    const float* cent = (const float*)d_in[2];
    float* out = (float*)d_out;
    char* ws = (char*)d_ws;

    ushort* a_t  = (ushort*)(ws + 0);
    ushort* Wb   = (ushort*)(ws + 13107200);
    float*  asum = (float*)(ws + 13172736);
    float*  rn2  = (float*)(ws + 13189120);
    float*  gn   = (float*)(ws + 13205504);

    hipMemsetAsync(asum, 0, 64 * 64 * sizeof(float), stream);
    hipMemsetAsync(d_out, 0, (size_t)out_size * sizeof(float), stream);

    hipLaunchKernelGGL(k0_wb,       dim3(128),      dim3(256), 0, stream, W, Wb);
    hipLaunchKernelGGL(k2g_gemm1,   dim3(25, 64),   dim3(256), 0, stream, x, Wb, a_t, asum);
    hipLaunchKernelGGL(k3_gemm2,    dim3(2, 64, 5), dim3(256), 0, stream, a_t, x, out);
    hipLaunchKernelGGL(k4a_rownorm, dim3(1024),     dim3(256), 0, stream, out, asum, cent, rn2);
    hipLaunchKernelGGL(k4b_gn,      dim3(64),       dim3(64),  0, stream, rn2, gn);
    hipLaunchKernelGGL(k4c_final,   dim3(2048),     dim3(256), 0, stream, out, asum, cent, rn2, gn);
}